// Round 1
// baseline (1443.005 us; speedup 1.0000x reference)
//
#include <hip/hip_runtime.h>
#include <cstdint>

// Problem constants
#define Bc 32
#define Lc 2048
#define Hc 512
#define Cc 50
#define Mc (Bc*Lc)   // 65536 rows

// ---------------------------------------------------------------------------
// GEMM: Out = f(A @ Bm^T), A is (M,K) row-major, Bm is (N,K) row-major.
// mode 0: Out = tanh(acc)                      (ldo = N = 512)
// mode 1: Out = A[m, j] + tanh(acc)            (N == K == 512, ldo = 512)
// mode 2: Out = acc, scalar stores, guard j<N  (N = 50, ldo = 50)
// Tiles: BM=BN=64, BK=16, 256 threads, 4x4 microtile.
// LDS rows padded to 68 floats so &As[k][4*t] is 16B-aligned (ds_read_b128).
// ---------------------------------------------------------------------------
__global__ __launch_bounds__(256)
void gemm_bt_kernel(const float* __restrict__ A, const float* __restrict__ Bm,
                    float* __restrict__ Out, int N, int K, int ldo, int mode)
{
    __shared__ float As[16][68];
    __shared__ float Bs[16][68];
    const int tid = threadIdx.x;
    const int i0  = blockIdx.x * 64;
    const int j0  = blockIdx.y * 64;
    const int lr  = tid >> 2;          // 0..63: row of A-tile / row of Bm-tile
    const int lc4 = (tid & 3) << 2;    // 0,4,8,12: k offset (float4)
    const int tx4 = (tid & 15) << 2;   // col quad within tile
    const int ty4 = (tid >> 4) << 2;   // row quad within tile

    float acc[4][4] = {{0.f,0.f,0.f,0.f},{0.f,0.f,0.f,0.f},
                       {0.f,0.f,0.f,0.f},{0.f,0.f,0.f,0.f}};

    for (int k0 = 0; k0 < K; k0 += 16) {
        float4 av = *(const float4*)(A + (size_t)(i0 + lr) * K + k0 + lc4);
        float4 bv = make_float4(0.f, 0.f, 0.f, 0.f);
        if (j0 + lr < N)
            bv = *(const float4*)(Bm + (size_t)(j0 + lr) * K + k0 + lc4);
        As[lc4+0][lr] = av.x; As[lc4+1][lr] = av.y;
        As[lc4+2][lr] = av.z; As[lc4+3][lr] = av.w;
        Bs[lc4+0][lr] = bv.x; Bs[lc4+1][lr] = bv.y;
        Bs[lc4+2][lr] = bv.z; Bs[lc4+3][lr] = bv.w;
        __syncthreads();
        #pragma unroll
        for (int k = 0; k < 16; ++k) {
            float4 af = *(const float4*)&As[k][ty4];
            float4 bf = *(const float4*)&Bs[k][tx4];
            float ar[4] = {af.x, af.y, af.z, af.w};
            float br[4] = {bf.x, bf.y, bf.z, bf.w};
            #pragma unroll
            for (int r = 0; r < 4; ++r)
                #pragma unroll
                for (int c = 0; c < 4; ++c)
                    acc[r][c] = fmaf(ar[r], br[c], acc[r][c]);
        }
        __syncthreads();
    }

    #pragma unroll
    for (int r = 0; r < 4; ++r) {
        const int m = i0 + ty4 + r;
        const size_t orow = (size_t)m * ldo;
        if (mode == 2) {
            #pragma unroll
            for (int c = 0; c < 4; ++c) {
                int col = j0 + tx4 + c;
                if (col < N) Out[orow + col] = acc[r][c];
            }
        } else if (mode == 0) {
            float4 o;
            o.x = tanhf(acc[r][0]); o.y = tanhf(acc[r][1]);
            o.z = tanhf(acc[r][2]); o.w = tanhf(acc[r][3]);
            *(float4*)(Out + orow + j0 + tx4) = o;
        } else { // mode 1: S = P1 + tanh(P1 @ W2^T); here A == P1 and j indexes K
            float4 prev = *(const float4*)(A + (size_t)m * K + j0 + tx4);
            float4 o;
            o.x = prev.x + tanhf(acc[r][0]); o.y = prev.y + tanhf(acc[r][1]);
            o.z = prev.z + tanhf(acc[r][2]); o.w = prev.w + tanhf(acc[r][3]);
            *(float4*)(Out + orow + j0 + tx4) = o;
        }
    }
}

// ---------------------------------------------------------------------------
// sent_lens dtype hedge: reference says int64, harness doc says int32.
// If the buffer is little-endian int64, all odd int32 words of the first
// 128 B are 0 (lens in [1,2048]); if int32, they are lens values >= 1.
// Unambiguous. Writes normalized int32 lens[32] into workspace.
// ---------------------------------------------------------------------------
__global__ __launch_bounds__(64)
void normalize_lens_kernel(const int* __restrict__ raw, int* __restrict__ lens)
{
    __shared__ int is64;
    if (threadIdx.x == 0) {
        int orv = 0;
        for (int i = 1; i < 32; i += 2) orv |= raw[i];
        is64 = (orv == 0) ? 1 : 0;
    }
    __syncthreads();
    int b = threadIdx.x;
    if (b < Bc) lens[b] = is64 ? raw[2*b] : raw[b];
}

// ---------------------------------------------------------------------------
// kq-fill (last-valid) + avgpool3(count_include_pad=False) + softmax + mask.
// One thread per (b,l); C=50 row kept in registers.
// ---------------------------------------------------------------------------
__global__ __launch_bounds__(256)
void pool_softmax_kernel(const float* __restrict__ P3, const int* __restrict__ lens,
                         float* __restrict__ out_attn, float* __restrict__ out_smooth)
{
    const int idx = blockIdx.x * 256 + threadIdx.x;   // b*L + l
    const int b = idx >> 11;
    const int l = idx & (Lc - 1);
    const int len = lens[b];
    const float* base = P3 + (size_t)b * Lc * Cc;

    const int  r0 = min(l, len - 1);
    const bool hm = (l > 0);
    const bool hp = (l < Lc - 1);
    const int  rm = hm ? min(l - 1, len - 1) : 0;
    const int  rp = hp ? min(l + 1, len - 1) : 0;
    const float cnt = 1.f + (hm ? 1.f : 0.f) + (hp ? 1.f : 0.f);

    float sm[Cc];
    float mx = -1e30f;
    #pragma unroll
    for (int c = 0; c < Cc; ++c) {
        float s = base[(size_t)r0 * Cc + c];
        if (hm) s += base[(size_t)rm * Cc + c];
        if (hp) s += base[(size_t)rp * Cc + c];
        s = s / cnt;
        sm[c] = s;
        mx = fmaxf(mx, s);
    }
    float* srow = out_smooth + (size_t)idx * Cc;
    #pragma unroll
    for (int c = 0; c < Cc; ++c) srow[c] = sm[c];

    float sum = 0.f;
    #pragma unroll
    for (int c = 0; c < Cc; ++c) {
        float e = __expf(sm[c] - mx);
        sm[c] = e;
        sum += e;
    }
    const float inv = 1.f / sum;
    const bool valid = (l < len);
    float* arow = out_attn + (size_t)idx * Cc;
    #pragma unroll
    for (int c = 0; c < Cc; ++c) arow[c] = valid ? sm[c] * inv : 0.f;
}

// ---------------------------------------------------------------------------
// class_inputs[b,c,h] = sum_l attn[b,l,c] * V[b,l,h]
// Block: (b, h-chunk of 256, l-chunk of 512). 256 thr = 64 h-lanes x 4 c-groups.
// Stage 32 L-rows of V (32x256 f32 = 32 KiB) + attn (32x50) in LDS.
// attn reads are wave-broadcast (all 64 lanes of a wave share one c-group).
// Partial results atomicAdd'ed (4 l-chunks collide); out region pre-zeroed.
// ---------------------------------------------------------------------------
__global__ __launch_bounds__(256)
void class_inputs_kernel(const float* __restrict__ attn, const float* __restrict__ V,
                         float* __restrict__ out_class)
{
    __shared__ float vs[32][256];
    __shared__ float as_flat[32 * Cc + 4];
    const int b  = blockIdx.x;
    const int h0 = blockIdx.y * 256;
    const int l0 = blockIdx.z * 512;
    const int tid = threadIdx.x;
    const int hl = tid & 63;    // h lane (float4 -> 4 h's)
    const int cg = tid >> 6;    // c group: c = cg*13 + i

    float4 acc[13];
    #pragma unroll
    for (int i = 0; i < 13; ++i) acc[i] = make_float4(0.f, 0.f, 0.f, 0.f);

    for (int ls = l0; ls < l0 + 512; ls += 32) {
        for (int f4 = tid; f4 < 2048; f4 += 256) {         // 32*256/4
            int li = f4 >> 6;
            int hh = (f4 & 63) << 2;
            *(float4*)&vs[li][hh] =
                *(const float4*)(V + ((size_t)(b * Lc + ls + li)) * Hc + h0 + hh);
        }
        for (int f = tid; f < 32 * Cc; f += 256)
            as_flat[f] = attn[((size_t)(b * Lc + ls)) * Cc + f];
        __syncthreads();
        for (int li = 0; li < 32; ++li) {
            float4 v = *(const float4*)&vs[li][hl << 2];
            const float* ar = &as_flat[li * Cc + cg * 13];
            #pragma unroll
            for (int i = 0; i < 13; ++i) {
                float a = (cg * 13 + i < Cc) ? ar[i] : 0.f;
                acc[i].x = fmaf(a, v.x, acc[i].x);
                acc[i].y = fmaf(a, v.y, acc[i].y);
                acc[i].z = fmaf(a, v.z, acc[i].z);
                acc[i].w = fmaf(a, v.w, acc[i].w);
            }
        }
        __syncthreads();
    }
    #pragma unroll
    for (int i = 0; i < 13; ++i) {
        int c = cg * 13 + i;
        if (c < Cc) {
            float* o = out_class + ((size_t)b * Cc + c) * Hc + h0 + (hl << 2);
            atomicAdd(o + 0, acc[i].x);
            atomicAdd(o + 1, acc[i].y);
            atomicAdd(o + 2, acc[i].z);
            atomicAdd(o + 3, acc[i].w);
        }
    }
}

// ---------------------------------------------------------------------------
// Workspace layout (needs exactly 256 MiB):
//   [0, 128MiB)      P1 (65536 x 512 f32)   -- dead after GEMM2
//   [128MiB, 256MiB) S  (65536 x 512 f32)
//   [0, 12.5MiB)     P3 (65536 x 50 f32)    -- overlays dead P1
//   [12.5MiB + ...]  lens (32 x i32)        -- in dead P1 zone, past P3
// ---------------------------------------------------------------------------
extern "C" void kernel_launch(void* const* d_in, const int* in_sizes, int n_in,
                              void* d_out, int out_size, void* d_ws, size_t ws_size,
                              hipStream_t stream)
{
    const float* keys     = (const float*)d_in[0];
    const float* vals     = (const float*)d_in[1];
    const int*   lens_raw = (const int*)d_in[2];
    const float* W1       = (const float*)d_in[3];
    const float* W2       = (const float*)d_in[4];
    const float* W3       = (const float*)d_in[5];

    float* P1 = (float*)d_ws;
    float* S  = (float*)d_ws + (size_t)Mc * Hc;
    float* P3 = (float*)d_ws;  // overlays P1 (dead by then)
    int*   lens = (int*)((char*)d_ws + (size_t)Mc * Cc * 4);

    float* out_attn   = (float*)d_out;
    float* out_class  = out_attn + (size_t)Bc * Lc * Cc;
    float* out_smooth = out_class + (size_t)Bc * Cc * Hc;

    // zero the atomic-accumulated class_inputs region (d_out is poisoned 0xAA)
    hipMemsetAsync(out_class, 0, (size_t)Bc * Cc * Hc * sizeof(float), stream);

    // P1 = tanh(X @ W1^T)
    gemm_bt_kernel<<<dim3(Mc/64, Hc/64), 256, 0, stream>>>(keys, W1, P1, Hc, Hc, Hc, 0);
    // S = P1 + tanh(P1 @ W2^T)
    gemm_bt_kernel<<<dim3(Mc/64, Hc/64), 256, 0, stream>>>(P1, W2, S, Hc, Hc, Hc, 1);
    // P3 = S @ W3^T   (N = 50)
    gemm_bt_kernel<<<dim3(Mc/64, 1), 256, 0, stream>>>(S, W3, P3, Cc, Hc, Cc, 2);
    // lens dtype normalization (int64 vs int32 auto-detect)
    normalize_lens_kernel<<<1, 64, 0, stream>>>(lens_raw, lens);
    // kq fill + avgpool3 + softmax + mask
    pool_softmax_kernel<<<Mc/256, 256, 0, stream>>>(P3, lens, out_attn, out_smooth);
    // class_inputs = attn^T @ V (per batch)
    class_inputs_kernel<<<dim3(Bc, Hc/256, Lc/512), 256, 0, stream>>>(out_attn, vals, out_class);
}

// Round 2
// 690.842 us; speedup vs baseline: 2.0888x; 2.0888x over previous
//
#include <hip/hip_runtime.h>
#include <cstdint>

// Problem constants
#define Bc 32
#define Lc 2048
#define Hc 512
#define Cc 50
#define Mc (Bc*Lc)   // 65536 rows

typedef short s8v   __attribute__((ext_vector_type(8)));   // 8 bf16 (4 VGPRs)
typedef float f4v   __attribute__((ext_vector_type(4)));   // MFMA C/D

__device__ inline unsigned short f2bf(float f) {            // RNE fp32->bf16
    unsigned int u = __float_as_uint(f);
    u += 0x7fffu + ((u >> 16) & 1u);
    return (unsigned short)(u >> 16);
}
__device__ inline float bf2f(unsigned short h) {
    return __uint_as_float(((unsigned int)h) << 16);
}
// async global->LDS, 16 B per lane; lds base must be wave-uniform, lane i
// deposits at base + i*16 (guide §5: contiguous, no padding).
__device__ inline void gl_lds16(const unsigned short* g, unsigned short* l) {
    __builtin_amdgcn_global_load_lds(
        (const __attribute__((address_space(1))) unsigned int*)g,
        (__attribute__((address_space(3))) unsigned int*)l, 16, 0, 0);
}

// ---------------------------------------------------------------------------
// fp32 -> bf16 bulk convert (keys). 8 elements/thread.
// ---------------------------------------------------------------------------
__global__ __launch_bounds__(256)
void f32_to_bf16_kernel(const float* __restrict__ in, unsigned short* __restrict__ out)
{
    size_t i = ((size_t)blockIdx.x * 256 + threadIdx.x) * 8;
    float4 a = *(const float4*)(in + i);
    float4 b = *(const float4*)(in + i + 4);
    s8v o;
    o[0]=f2bf(a.x); o[1]=f2bf(a.y); o[2]=f2bf(a.z); o[3]=f2bf(a.w);
    o[4]=f2bf(b.x); o[5]=f2bf(b.y); o[6]=f2bf(b.z); o[7]=f2bf(b.w);
    *(s8v*)(out + i) = o;
}

// ---------------------------------------------------------------------------
// Convert W1, W2 -> bf16; W3 (50x512) -> bf16 padded to 64x512 (zero rows).
// 557056 total elements, 8 per thread -> 272 blocks of 256.
// ---------------------------------------------------------------------------
__global__ __launch_bounds__(256)
void convert_weights_kernel(const float* __restrict__ W1, const float* __restrict__ W2,
                            const float* __restrict__ W3,
                            unsigned short* __restrict__ W1b,
                            unsigned short* __restrict__ W2b,
                            unsigned short* __restrict__ W3b)
{
    int e = (blockIdx.x * 256 + threadIdx.x) * 8;
    if (e >= 524288) {                       // W3 padded region
        int off = e - 524288;                // row = off>>9 in 64x512
        int row = off >> 9;
        s8v o;
        #pragma unroll
        for (int j = 0; j < 8; ++j)
            o[j] = (row < Cc) ? (short)f2bf(W3[off + j]) : (short)0;
        *(s8v*)(W3b + off) = o;
        return;
    }
    const float* src = (e < 262144) ? W1 : W2;
    unsigned short* dst = (e < 262144) ? W1b : W2b;
    int off = (e < 262144) ? e : e - 262144;
    float4 a = *(const float4*)(src + off);
    float4 b = *(const float4*)(src + off + 4);
    s8v o;
    o[0]=f2bf(a.x); o[1]=f2bf(a.y); o[2]=f2bf(a.z); o[3]=f2bf(a.w);
    o[4]=f2bf(b.x); o[5]=f2bf(b.y); o[6]=f2bf(b.z); o[7]=f2bf(b.w);
    *(s8v*)(dst + off) = o;
}

// ---------------------------------------------------------------------------
// MFMA GEMM: Out = f(A @ W^T), A (M,512) bf16, W (512,512) bf16, Out (M,512) bf16.
// mode 0: Out = bf16(tanh(acc))           (P1 = tanh(keys@W1^T))
// mode 1: Out = bf16(A[m,j] + tanh(acc))  (S = P1 + tanh(P1@W2^T))
// 128x128 tile, BK=32, 256 thr = 4 waves, each wave 64x64 = 4x4 MFMA tiles.
// Staging via global_load_lds width 16 (m97 structure).
// Fragment layouts (guide §3, HW-verified):
//   A/B frag: elem (lane&15) row/col, k = (lane>>4)*8 + j  -> contiguous 16 B
//   C/D:      col = lane&15, row = (lane>>4)*4 + v
// ---------------------------------------------------------------------------
__global__ __launch_bounds__(256)
void mfma_gemm512(const unsigned short* __restrict__ Ab,
                  const unsigned short* __restrict__ Wb,
                  unsigned short* __restrict__ Ob, int mode)
{
    __shared__ alignas(16) unsigned short As[128 * 32];
    __shared__ alignas(16) unsigned short Bs[128 * 32];
    const int tid = threadIdx.x;
    const int w = tid >> 6, l = tid & 63;
    const int j0 = blockIdx.x * 128;     // N-tile fastest -> A rows shared in L2
    const int i0 = blockIdx.y * 128;

    // staging: slot s = w*64 + l (issue0), +256 (issue1); row = s>>2, k16 = s&3
    const int sr  = w * 16 + (l >> 2);   // 0..63
    const int kg8 = (l & 3) * 8;         // bf16 offset within 32-k tile
    const unsigned short* Ag0 = Ab + (size_t)(i0 + sr) * 512 + kg8;
    const unsigned short* Ag1 = Ag0 + (size_t)64 * 512;
    const unsigned short* Bg0 = Wb + (size_t)(j0 + sr) * 512 + kg8;
    const unsigned short* Bg1 = Bg0 + (size_t)64 * 512;
    unsigned short* Al0 = As + w * 512;
    unsigned short* Al1 = As + 2048 + w * 512;
    unsigned short* Bl0 = Bs + w * 512;
    unsigned short* Bl1 = Bs + 2048 + w * 512;

    const int wm = (w & 1) * 64, wn = (w >> 1) * 64;
    const int fr = l & 15;
    const int fq = (l >> 4) * 8;

    f4v acc[4][4];
    #pragma unroll
    for (int r = 0; r < 4; ++r)
        #pragma unroll
        for (int c = 0; c < 4; ++c) acc[r][c] = (f4v){0.f, 0.f, 0.f, 0.f};

    for (int k0 = 0; k0 < 512; k0 += 32) {
        gl_lds16(Ag0 + k0, Al0);
        gl_lds16(Ag1 + k0, Al1);
        gl_lds16(Bg0 + k0, Bl0);
        gl_lds16(Bg1 + k0, Bl1);
        __syncthreads();
        s8v af[4], bf[4];
        #pragma unroll
        for (int r = 0; r < 4; ++r)
            af[r] = *(const s8v*)&As[(wm + r * 16 + fr) * 32 + fq];
        #pragma unroll
        for (int c = 0; c < 4; ++c)
            bf[c] = *(const s8v*)&Bs[(wn + c * 16 + fr) * 32 + fq];
        #pragma unroll
        for (int r = 0; r < 4; ++r)
            #pragma unroll
            for (int c = 0; c < 4; ++c)
                acc[r][c] = __builtin_amdgcn_mfma_f32_16x16x32_bf16(
                    af[r], bf[c], acc[r][c], 0, 0, 0);
        __syncthreads();
    }

    #pragma unroll
    for (int r = 0; r < 4; ++r)
        #pragma unroll
        for (int v = 0; v < 4; ++v) {
            const int row = i0 + wm + r * 16 + (l >> 4) * 4 + v;
            #pragma unroll
            for (int c = 0; c < 4; ++c) {
                const int col = j0 + wn + c * 16 + fr;
                float x = tanhf(acc[r][c][v]);
                if (mode) x += bf2f(Ab[(size_t)row * 512 + col]);
                Ob[(size_t)row * 512 + col] = f2bf(x);
            }
        }
}

// ---------------------------------------------------------------------------
// MFMA GEMM3: P3 = S @ W3^T, S (M,512) bf16, W3b (64,512) bf16 zero-padded,
// P3 (M,50) fp32. 128x64 tile; wave w does rows [w*32, w*32+32): 2x4 tiles.
// ---------------------------------------------------------------------------
__global__ __launch_bounds__(256)
void mfma_gemm_p3(const unsigned short* __restrict__ Sb,
                  const unsigned short* __restrict__ W3b,
                  float* __restrict__ P3)
{
    __shared__ alignas(16) unsigned short As[128 * 32];
    __shared__ alignas(16) unsigned short Bs[64 * 32];
    const int tid = threadIdx.x;
    const int w = tid >> 6, l = tid & 63;
    const int i0 = blockIdx.x * 128;

    const int sr  = w * 16 + (l >> 2);
    const int kg8 = (l & 3) * 8;
    const unsigned short* Ag0 = Sb + (size_t)(i0 + sr) * 512 + kg8;
    const unsigned short* Ag1 = Ag0 + (size_t)64 * 512;
    const unsigned short* Bg  = W3b + (size_t)sr * 512 + kg8;  // 64 rows, 1 issue
    unsigned short* Al0 = As + w * 512;
    unsigned short* Al1 = As + 2048 + w * 512;
    unsigned short* Bl  = Bs + w * 512;

    const int wm = w * 32;
    const int fr = l & 15;
    const int fq = (l >> 4) * 8;

    f4v acc[2][4];
    #pragma unroll
    for (int r = 0; r < 2; ++r)
        #pragma unroll
        for (int c = 0; c < 4; ++c) acc[r][c] = (f4v){0.f, 0.f, 0.f, 0.f};

    for (int k0 = 0; k0 < 512; k0 += 32) {
        gl_lds16(Ag0 + k0, Al0);
        gl_lds16(Ag1 + k0, Al1);
        gl_lds16(Bg + k0, Bl);
        __syncthreads();
        s8v af[2], bf[4];
        #pragma unroll
        for (int r = 0; r < 2; ++r)
            af[r] = *(const s8v*)&As[(wm + r * 16 + fr) * 32 + fq];
        #pragma unroll
        for (int c = 0; c < 4; ++c)
            bf[c] = *(const s8v*)&Bs[(c * 16 + fr) * 32 + fq];
        #pragma unroll
        for (int r = 0; r < 2; ++r)
            #pragma unroll
            for (int c = 0; c < 4; ++c)
                acc[r][c] = __builtin_amdgcn_mfma_f32_16x16x32_bf16(
                    af[r], bf[c], acc[r][c], 0, 0, 0);
        __syncthreads();
    }

    #pragma unroll
    for (int r = 0; r < 2; ++r)
        #pragma unroll
        for (int v = 0; v < 4; ++v) {
            const int row = i0 + wm + r * 16 + (l >> 4) * 4 + v;
            #pragma unroll
            for (int c = 0; c < 4; ++c) {
                const int col = c * 16 + fr;
                if (col < Cc) P3[(size_t)row * Cc + col] = acc[r][c][v];
            }
        }
}

// ---------------------------------------------------------------------------
// sent_lens dtype hedge (int64 vs int32 auto-detect), as round 1.
// ---------------------------------------------------------------------------
__global__ __launch_bounds__(64)
void normalize_lens_kernel(const int* __restrict__ raw, int* __restrict__ lens)
{
    __shared__ int is64;
    if (threadIdx.x == 0) {
        int orv = 0;
        for (int i = 1; i < 32; i += 2) orv |= raw[i];
        is64 = (orv == 0) ? 1 : 0;
    }
    __syncthreads();
    int b = threadIdx.x;
    if (b < Bc) lens[b] = is64 ? raw[2*b] : raw[b];
}

// ---------------------------------------------------------------------------
// kq-fill (last-valid) + avgpool3(count_include_pad=False) + softmax + mask.
// ---------------------------------------------------------------------------
__global__ __launch_bounds__(256)
void pool_softmax_kernel(const float* __restrict__ P3, const int* __restrict__ lens,
                         float* __restrict__ out_attn, float* __restrict__ out_smooth)
{
    const int idx = blockIdx.x * 256 + threadIdx.x;   // b*L + l
    const int b = idx >> 11;
    const int l = idx & (Lc - 1);
    const int len = lens[b];
    const float* base = P3 + (size_t)b * Lc * Cc;

    const int  r0 = min(l, len - 1);
    const bool hm = (l > 0);
    const bool hp = (l < Lc - 1);
    const int  rm = hm ? min(l - 1, len - 1) : 0;
    const int  rp = hp ? min(l + 1, len - 1) : 0;
    const float cnt = 1.f + (hm ? 1.f : 0.f) + (hp ? 1.f : 0.f);

    float sm[Cc];
    float mx = -1e30f;
    #pragma unroll
    for (int c = 0; c < Cc; ++c) {
        float s = base[(size_t)r0 * Cc + c];
        if (hm) s += base[(size_t)rm * Cc + c];
        if (hp) s += base[(size_t)rp * Cc + c];
        s = s / cnt;
        sm[c] = s;
        mx = fmaxf(mx, s);
    }
    float* srow = out_smooth + (size_t)idx * Cc;
    #pragma unroll
    for (int c = 0; c < Cc; ++c) srow[c] = sm[c];

    float sum = 0.f;
    #pragma unroll
    for (int c = 0; c < Cc; ++c) {
        float e = __expf(sm[c] - mx);
        sm[c] = e;
        sum += e;
    }
    const float inv = 1.f / sum;
    const bool valid = (l < len);
    float* arow = out_attn + (size_t)idx * Cc;
    #pragma unroll
    for (int c = 0; c < Cc; ++c) arow[c] = valid ? sm[c] * inv : 0.f;
}

// ---------------------------------------------------------------------------
// class_inputs[b,c,h] = sum_l attn[b,l,c] * V[b,l,h]  (unchanged from round 1)
// ---------------------------------------------------------------------------
__global__ __launch_bounds__(256)
void class_inputs_kernel(const float* __restrict__ attn, const float* __restrict__ V,
                         float* __restrict__ out_class)
{
    __shared__ float vs[32][256];
    __shared__ float as_flat[32 * Cc + 4];
    const int b  = blockIdx.x;
    const int h0 = blockIdx.y * 256;
    const int l0 = blockIdx.z * 512;
    const int tid = threadIdx.x;
    const int hl = tid & 63;
    const int cg = tid >> 6;

    float4 acc[13];
    #pragma unroll
    for (int i = 0; i < 13; ++i) acc[i] = make_float4(0.f, 0.f, 0.f, 0.f);

    for (int ls = l0; ls < l0 + 512; ls += 32) {
        for (int f4 = tid; f4 < 2048; f4 += 256) {
            int li = f4 >> 6;
            int hh = (f4 & 63) << 2;
            *(float4*)&vs[li][hh] =
                *(const float4*)(V + ((size_t)(b * Lc + ls + li)) * Hc + h0 + hh);
        }
        for (int f = tid; f < 32 * Cc; f += 256)
            as_flat[f] = attn[((size_t)(b * Lc + ls)) * Cc + f];
        __syncthreads();
        for (int li = 0; li < 32; ++li) {
            float4 v = *(const float4*)&vs[li][hl << 2];
            const float* ar = &as_flat[li * Cc + cg * 13];
            #pragma unroll
            for (int i = 0; i < 13; ++i) {
                float a = (cg * 13 + i < Cc) ? ar[i] : 0.f;
                acc[i].x = fmaf(a, v.x, acc[i].x);
                acc[i].y = fmaf(a, v.y, acc[i].y);
                acc[i].z = fmaf(a, v.z, acc[i].z);
                acc[i].w = fmaf(a, v.w, acc[i].w);
            }
        }
        __syncthreads();
    }
    #pragma unroll
    for (int i = 0; i < 13; ++i) {
        int c = cg * 13 + i;
        if (c < Cc) {
            float* o = out_class + ((size_t)b * Cc + c) * Hc + h0 + (hl << 2);
            atomicAdd(o + 0, acc[i].x);
            atomicAdd(o + 1, acc[i].y);
            atomicAdd(o + 2, acc[i].z);
            atomicAdd(o + 3, acc[i].w);
        }
    }
}

// ---------------------------------------------------------------------------
// Workspace layout (~216 MiB used):
//   Akv  bf16 Mc x Hc     @ 0        (64 MiB)
//   P1b  bf16 Mc x Hc     @ 64 MiB
//   Sb   bf16 Mc x Hc     @ 128 MiB
//   P3   fp32 Mc x Cc     @ 192 MiB  (12.5 MiB)
//   W1b/W2b bf16 512x512, W3b bf16 64x512, lens i32  (after P3)
// ---------------------------------------------------------------------------
extern "C" void kernel_launch(void* const* d_in, const int* in_sizes, int n_in,
                              void* d_out, int out_size, void* d_ws, size_t ws_size,
                              hipStream_t stream)
{
    const float* keys     = (const float*)d_in[0];
    const float* vals     = (const float*)d_in[1];
    const int*   lens_raw = (const int*)d_in[2];
    const float* W1       = (const float*)d_in[3];
    const float* W2       = (const float*)d_in[4];
    const float* W3       = (const float*)d_in[5];

    char* ws = (char*)d_ws;
    unsigned short* Akv = (unsigned short*)ws;
    unsigned short* P1b = (unsigned short*)(ws + (size_t)Mc * Hc * 2);
    unsigned short* Sb  = (unsigned short*)(ws + (size_t)Mc * Hc * 4);
    float*          P3  = (float*)(ws + (size_t)Mc * Hc * 6);
    unsigned short* W1b = (unsigned short*)(ws + (size_t)Mc * Hc * 6 + (size_t)Mc * Cc * 4);
    unsigned short* W2b = W1b + Hc * Hc;
    unsigned short* W3b = W2b + Hc * Hc;
    int*            lens = (int*)(W3b + 64 * Hc);

    float* out_attn   = (float*)d_out;
    float* out_class  = out_attn + (size_t)Bc * Lc * Cc;
    float* out_smooth = out_class + (size_t)Bc * Cc * Hc;

    hipMemsetAsync(out_class, 0, (size_t)Bc * Cc * Hc * sizeof(float), stream);

    f32_to_bf16_kernel<<<(Mc * Hc / 8) / 256, 256, 0, stream>>>(keys, Akv);
    convert_weights_kernel<<<272, 256, 0, stream>>>(W1, W2, W3, W1b, W2b, W3b);

    // P1 = tanh(keys @ W1^T)   [bf16 out]
    mfma_gemm512<<<dim3(4, Mc / 128), 256, 0, stream>>>(Akv, W1b, P1b, 0);
    // S = P1 + tanh(P1 @ W2^T) [bf16 out]
    mfma_gemm512<<<dim3(4, Mc / 128), 256, 0, stream>>>(P1b, W2b, Sb, 1);
    // P3 = S @ W3^T            [fp32 out, N=50 padded to 64]
    mfma_gemm_p3<<<Mc / 128, 256, 0, stream>>>(Sb, W3b, P3);

    normalize_lens_kernel<<<1, 64, 0, stream>>>(lens_raw, lens);
    pool_softmax_kernel<<<Mc / 256, 256, 0, stream>>>(P3, lens, out_attn, out_smooth);
    class_inputs_kernel<<<dim3(Bc, Hc / 256, Lc / 512), 256, 0, stream>>>(out_attn, vals, out_class);
}

// Round 3
// 649.738 us; speedup vs baseline: 2.2209x; 1.0633x over previous
//
#include <hip/hip_runtime.h>
#include <cstdint>

// Problem constants
#define Bc 32
#define Lc 2048
#define Hc 512
#define Cc 50
#define Mc (Bc*Lc)   // 65536 rows

typedef short s8v   __attribute__((ext_vector_type(8)));   // 8 bf16 (4 VGPRs)
typedef float f4v   __attribute__((ext_vector_type(4)));   // MFMA C/D

__device__ inline unsigned short f2bf(float f) {            // RNE fp32->bf16
    unsigned int u = __float_as_uint(f);
    u += 0x7fffu + ((u >> 16) & 1u);
    return (unsigned short)(u >> 16);
}
__device__ inline float bf2f(unsigned short h) {
    return __uint_as_float(((unsigned int)h) << 16);
}
__device__ inline void gl_lds16(const unsigned short* g, unsigned short* l) {
    __builtin_amdgcn_global_load_lds(
        (const __attribute__((address_space(1))) unsigned int*)g,
        (__attribute__((address_space(3))) unsigned int*)l, 16, 0, 0);
}

// ---------------------------------------------------------------------------
// fp32 -> bf16 bulk convert (keys). 8 elements/thread.
// ---------------------------------------------------------------------------
__global__ __launch_bounds__(256)
void f32_to_bf16_kernel(const float* __restrict__ in, unsigned short* __restrict__ out)
{
    size_t i = ((size_t)blockIdx.x * 256 + threadIdx.x) * 8;
    float4 a = *(const float4*)(in + i);
    float4 b = *(const float4*)(in + i + 4);
    s8v o;
    o[0]=f2bf(a.x); o[1]=f2bf(a.y); o[2]=f2bf(a.z); o[3]=f2bf(a.w);
    o[4]=f2bf(b.x); o[5]=f2bf(b.y); o[6]=f2bf(b.z); o[7]=f2bf(b.w);
    *(s8v*)(out + i) = o;
}

// ---------------------------------------------------------------------------
// Convert W1, W2 -> bf16; W3 (50x512) -> bf16 padded to 64x512 (zero rows).
// ---------------------------------------------------------------------------
__global__ __launch_bounds__(256)
void convert_weights_kernel(const float* __restrict__ W1, const float* __restrict__ W2,
                            const float* __restrict__ W3,
                            unsigned short* __restrict__ W1b,
                            unsigned short* __restrict__ W2b,
                            unsigned short* __restrict__ W3b)
{
    int e = (blockIdx.x * 256 + threadIdx.x) * 8;
    if (e >= 524288) {                       // W3 padded region
        int off = e - 524288;
        int row = off >> 9;
        s8v o;
        #pragma unroll
        for (int j = 0; j < 8; ++j)
            o[j] = (row < Cc) ? (short)f2bf(W3[off + j]) : (short)0;
        *(s8v*)(W3b + off) = o;
        return;
    }
    const float* src = (e < 262144) ? W1 : W2;
    unsigned short* dst = (e < 262144) ? W1b : W2b;
    int off = (e < 262144) ? e : e - 262144;
    float4 a = *(const float4*)(src + off);
    float4 b = *(const float4*)(src + off + 4);
    s8v o;
    o[0]=f2bf(a.x); o[1]=f2bf(a.y); o[2]=f2bf(a.z); o[3]=f2bf(a.w);
    o[4]=f2bf(b.x); o[5]=f2bf(b.y); o[6]=f2bf(b.z); o[7]=f2bf(b.w);
    *(s8v*)(dst + off) = o;
}

// ---------------------------------------------------------------------------
// MFMA GEMM: Out = f(A @ W^T), 128x128 tile, BK=32, m97 structure (unchanged).
// mode 0: Out = bf16(tanh(acc)); mode 1: Out = bf16(A[m,j] + tanh(acc))
// ---------------------------------------------------------------------------
__global__ __launch_bounds__(256)
void mfma_gemm512(const unsigned short* __restrict__ Ab,
                  const unsigned short* __restrict__ Wb,
                  unsigned short* __restrict__ Ob, int mode)
{
    __shared__ alignas(16) unsigned short As[128 * 32];
    __shared__ alignas(16) unsigned short Bs[128 * 32];
    const int tid = threadIdx.x;
    const int w = tid >> 6, l = tid & 63;
    const int j0 = blockIdx.x * 128;
    const int i0 = blockIdx.y * 128;

    const int sr  = w * 16 + (l >> 2);
    const int kg8 = (l & 3) * 8;
    const unsigned short* Ag0 = Ab + (size_t)(i0 + sr) * 512 + kg8;
    const unsigned short* Ag1 = Ag0 + (size_t)64 * 512;
    const unsigned short* Bg0 = Wb + (size_t)(j0 + sr) * 512 + kg8;
    const unsigned short* Bg1 = Bg0 + (size_t)64 * 512;
    unsigned short* Al0 = As + w * 512;
    unsigned short* Al1 = As + 2048 + w * 512;
    unsigned short* Bl0 = Bs + w * 512;
    unsigned short* Bl1 = Bs + 2048 + w * 512;

    const int wm = (w & 1) * 64, wn = (w >> 1) * 64;
    const int fr = l & 15;
    const int fq = (l >> 4) * 8;

    f4v acc[4][4];
    #pragma unroll
    for (int r = 0; r < 4; ++r)
        #pragma unroll
        for (int c = 0; c < 4; ++c) acc[r][c] = (f4v){0.f, 0.f, 0.f, 0.f};

    for (int k0 = 0; k0 < 512; k0 += 32) {
        gl_lds16(Ag0 + k0, Al0);
        gl_lds16(Ag1 + k0, Al1);
        gl_lds16(Bg0 + k0, Bl0);
        gl_lds16(Bg1 + k0, Bl1);
        __syncthreads();
        s8v af[4], bf[4];
        #pragma unroll
        for (int r = 0; r < 4; ++r)
            af[r] = *(const s8v*)&As[(wm + r * 16 + fr) * 32 + fq];
        #pragma unroll
        for (int c = 0; c < 4; ++c)
            bf[c] = *(const s8v*)&Bs[(wn + c * 16 + fr) * 32 + fq];
        #pragma unroll
        for (int r = 0; r < 4; ++r)
            #pragma unroll
            for (int c = 0; c < 4; ++c)
                acc[r][c] = __builtin_amdgcn_mfma_f32_16x16x32_bf16(
                    af[r], bf[c], acc[r][c], 0, 0, 0);
        __syncthreads();
    }

    #pragma unroll
    for (int r = 0; r < 4; ++r)
        #pragma unroll
        for (int v = 0; v < 4; ++v) {
            const int row = i0 + wm + r * 16 + (l >> 4) * 4 + v;
            #pragma unroll
            for (int c = 0; c < 4; ++c) {
                const int col = j0 + wn + c * 16 + fr;
                float x = tanhf(acc[r][c][v]);
                if (mode) x += bf2f(Ab[(size_t)row * 512 + col]);
                Ob[(size_t)row * 512 + col] = f2bf(x);
            }
        }
}

// ---------------------------------------------------------------------------
// MFMA GEMM3: P3 = S @ W3^T (N=50 padded 64), fp32 out. (unchanged)
// ---------------------------------------------------------------------------
__global__ __launch_bounds__(256)
void mfma_gemm_p3(const unsigned short* __restrict__ Sb,
                  const unsigned short* __restrict__ W3b,
                  float* __restrict__ P3)
{
    __shared__ alignas(16) unsigned short As[128 * 32];
    __shared__ alignas(16) unsigned short Bs[64 * 32];
    const int tid = threadIdx.x;
    const int w = tid >> 6, l = tid & 63;
    const int i0 = blockIdx.x * 128;

    const int sr  = w * 16 + (l >> 2);
    const int kg8 = (l & 3) * 8;
    const unsigned short* Ag0 = Sb + (size_t)(i0 + sr) * 512 + kg8;
    const unsigned short* Ag1 = Ag0 + (size_t)64 * 512;
    const unsigned short* Bg  = W3b + (size_t)sr * 512 + kg8;
    unsigned short* Al0 = As + w * 512;
    unsigned short* Al1 = As + 2048 + w * 512;
    unsigned short* Bl  = Bs + w * 512;

    const int wm = w * 32;
    const int fr = l & 15;
    const int fq = (l >> 4) * 8;

    f4v acc[2][4];
    #pragma unroll
    for (int r = 0; r < 2; ++r)
        #pragma unroll
        for (int c = 0; c < 4; ++c) acc[r][c] = (f4v){0.f, 0.f, 0.f, 0.f};

    for (int k0 = 0; k0 < 512; k0 += 32) {
        gl_lds16(Ag0 + k0, Al0);
        gl_lds16(Ag1 + k0, Al1);
        gl_lds16(Bg + k0, Bl);
        __syncthreads();
        s8v af[2], bf[4];
        #pragma unroll
        for (int r = 0; r < 2; ++r)
            af[r] = *(const s8v*)&As[(wm + r * 16 + fr) * 32 + fq];
        #pragma unroll
        for (int c = 0; c < 4; ++c)
            bf[c] = *(const s8v*)&Bs[(c * 16 + fr) * 32 + fq];
        #pragma unroll
        for (int r = 0; r < 2; ++r)
            #pragma unroll
            for (int c = 0; c < 4; ++c)
                acc[r][c] = __builtin_amdgcn_mfma_f32_16x16x32_bf16(
                    af[r], bf[c], acc[r][c], 0, 0, 0);
        __syncthreads();
    }

    #pragma unroll
    for (int r = 0; r < 2; ++r)
        #pragma unroll
        for (int v = 0; v < 4; ++v) {
            const int row = i0 + wm + r * 16 + (l >> 4) * 4 + v;
            #pragma unroll
            for (int c = 0; c < 4; ++c) {
                const int col = c * 16 + fr;
                if (col < Cc) P3[(size_t)row * Cc + col] = acc[r][c][v];
            }
        }
}

// ---------------------------------------------------------------------------
// sent_lens dtype hedge (int64 vs int32 auto-detect).
// ---------------------------------------------------------------------------
__global__ __launch_bounds__(64)
void normalize_lens_kernel(const int* __restrict__ raw, int* __restrict__ lens)
{
    __shared__ int is64;
    if (threadIdx.x == 0) {
        int orv = 0;
        for (int i = 1; i < 32; i += 2) orv |= raw[i];
        is64 = (orv == 0) ? 1 : 0;
    }
    __syncthreads();
    int b = threadIdx.x;
    if (b < Bc) lens[b] = is64 ? raw[2*b] : raw[b];
}

// ---------------------------------------------------------------------------
// kq-fill + avgpool3(count_include_pad=False) + softmax + mask. (unchanged)
// ---------------------------------------------------------------------------
__global__ __launch_bounds__(256)
void pool_softmax_kernel(const float* __restrict__ P3, const int* __restrict__ lens,
                         float* __restrict__ out_attn, float* __restrict__ out_smooth)
{
    const int idx = blockIdx.x * 256 + threadIdx.x;   // b*L + l
    const int b = idx >> 11;
    const int l = idx & (Lc - 1);
    const int len = lens[b];
    const float* base = P3 + (size_t)b * Lc * Cc;

    const int  r0 = min(l, len - 1);
    const bool hm = (l > 0);
    const bool hp = (l < Lc - 1);
    const int  rm = hm ? min(l - 1, len - 1) : 0;
    const int  rp = hp ? min(l + 1, len - 1) : 0;
    const float cnt = 1.f + (hm ? 1.f : 0.f) + (hp ? 1.f : 0.f);

    float sm[Cc];
    float mx = -1e30f;
    #pragma unroll
    for (int c = 0; c < Cc; ++c) {
        float s = base[(size_t)r0 * Cc + c];
        if (hm) s += base[(size_t)rm * Cc + c];
        if (hp) s += base[(size_t)rp * Cc + c];
        s = s / cnt;
        sm[c] = s;
        mx = fmaxf(mx, s);
    }
    float* srow = out_smooth + (size_t)idx * Cc;
    #pragma unroll
    for (int c = 0; c < Cc; ++c) srow[c] = sm[c];

    float sum = 0.f;
    #pragma unroll
    for (int c = 0; c < Cc; ++c) {
        float e = __expf(sm[c] - mx);
        sm[c] = e;
        sum += e;
    }
    const float inv = 1.f / sum;
    const bool valid = (l < len);
    float* arow = out_attn + (size_t)idx * Cc;
    #pragma unroll
    for (int c = 0; c < Cc; ++c) arow[c] = valid ? sm[c] * inv : 0.f;
}

// ---------------------------------------------------------------------------
// class_inputs[b,c,h] = sum_l attn[b,l,c] * V[b,l,h]  -- v3
// Grid (32 b, 2 h-chunks of 256, 8 l-chunks of 256); 256 thr = 64 h-quads x
// 4 c-groups of 13. V read DIRECT from global (float4, wave-coalesced 1 KiB;
// 4 waves hit the same lines -> L1). attn staged in LDS 64 l's at a time,
// padded layout as[li][cg*16 + j] so reads are wave-uniform ds_read_b128
// broadcasts (conflict-free). Only attn staging needs barriers.
// 52 independent FMA chains/thread hide latency at 2 blocks/CU.
// ---------------------------------------------------------------------------
__global__ __launch_bounds__(256)
void class_inputs_kernel(const float* __restrict__ attn, const float* __restrict__ V,
                         float* __restrict__ out_class)
{
    __shared__ float as[64 * 64];          // [li][cg*16+j], 16 KiB
    const int b  = blockIdx.x;
    const int h0 = blockIdx.y * 256;
    const int l0 = blockIdx.z * 256;
    const int tid = threadIdx.x;
    const int hl = tid & 63;               // h quad: h = h0 + hl*4
    const int cg = tid >> 6;               // == wave id -> wave-uniform

    float4 acc[13];
    #pragma unroll
    for (int i = 0; i < 13; ++i) acc[i] = make_float4(0.f, 0.f, 0.f, 0.f);

    const float* Vb = V + ((size_t)(b * Lc + l0)) * Hc + h0 + (hl << 2);

    for (int ls = 0; ls < 256; ls += 64) {
        // stage attn rows [l0+ls, l0+ls+64) into padded LDS
        const float* arow = attn + ((size_t)(b * Lc + l0 + ls)) * Cc;
        for (int f = tid; f < 64 * 52; f += 256) {
            int li = f / 52;
            int q  = f - li * 52;
            int g  = q / 13;
            int j  = q - g * 13;
            int c  = g * 13 + j;
            as[li * 64 + g * 16 + j] = (c < Cc) ? arow[li * Cc + c] : 0.f;
        }
        __syncthreads();
        const float* Vp = Vb + (size_t)ls * Hc;
        for (int li = 0; li < 64; ++li) {
            float4 v = *(const float4*)(Vp + (size_t)li * Hc);
            const float* ap = &as[li * 64 + cg * 16];
            f4v a0 = *(const f4v*)(ap);        // c 0..3   (broadcast)
            f4v a1 = *(const f4v*)(ap + 4);    // c 4..7
            f4v a2 = *(const f4v*)(ap + 8);    // c 8..11
            float a3 = ap[12];                 // c 12
            float ar[13] = {a0[0],a0[1],a0[2],a0[3], a1[0],a1[1],a1[2],a1[3],
                            a2[0],a2[1],a2[2],a2[3], a3};
            #pragma unroll
            for (int i = 0; i < 13; ++i) {
                acc[i].x = fmaf(ar[i], v.x, acc[i].x);
                acc[i].y = fmaf(ar[i], v.y, acc[i].y);
                acc[i].z = fmaf(ar[i], v.z, acc[i].z);
                acc[i].w = fmaf(ar[i], v.w, acc[i].w);
            }
        }
        __syncthreads();
    }

    #pragma unroll
    for (int i = 0; i < 13; ++i) {
        int c = cg * 13 + i;
        if (c < Cc) {
            float* o = out_class + ((size_t)b * Cc + c) * Hc + h0 + (hl << 2);
            atomicAdd(o + 0, acc[i].x);
            atomicAdd(o + 1, acc[i].y);
            atomicAdd(o + 2, acc[i].z);
            atomicAdd(o + 3, acc[i].w);
        }
    }
}

// ---------------------------------------------------------------------------
// Workspace layout (~216 MiB used): Akv | P1b | Sb | P3 | W1b W2b W3b lens
// ---------------------------------------------------------------------------
extern "C" void kernel_launch(void* const* d_in, const int* in_sizes, int n_in,
                              void* d_out, int out_size, void* d_ws, size_t ws_size,
                              hipStream_t stream)
{
    const float* keys     = (const float*)d_in[0];
    const float* vals     = (const float*)d_in[1];
    const int*   lens_raw = (const int*)d_in[2];
    const float* W1       = (const float*)d_in[3];
    const float* W2       = (const float*)d_in[4];
    const float* W3       = (const float*)d_in[5];

    char* ws = (char*)d_ws;
    unsigned short* Akv = (unsigned short*)ws;
    unsigned short* P1b = (unsigned short*)(ws + (size_t)Mc * Hc * 2);
    unsigned short* Sb  = (unsigned short*)(ws + (size_t)Mc * Hc * 4);
    float*          P3  = (float*)(ws + (size_t)Mc * Hc * 6);
    unsigned short* W1b = (unsigned short*)(ws + (size_t)Mc * Hc * 6 + (size_t)Mc * Cc * 4);
    unsigned short* W2b = W1b + Hc * Hc;
    unsigned short* W3b = W2b + Hc * Hc;
    int*            lens = (int*)(W3b + 64 * Hc);

    float* out_attn   = (float*)d_out;
    float* out_class  = out_attn + (size_t)Bc * Lc * Cc;
    float* out_smooth = out_class + (size_t)Bc * Cc * Hc;

    hipMemsetAsync(out_class, 0, (size_t)Bc * Cc * Hc * sizeof(float), stream);

    f32_to_bf16_kernel<<<(Mc * Hc / 8) / 256, 256, 0, stream>>>(keys, Akv);
    convert_weights_kernel<<<272, 256, 0, stream>>>(W1, W2, W3, W1b, W2b, W3b);

    // P1 = tanh(keys @ W1^T)   [bf16 out]
    mfma_gemm512<<<dim3(4, Mc / 128), 256, 0, stream>>>(Akv, W1b, P1b, 0);
    // S = P1 + tanh(P1 @ W2^T) [bf16 out]
    mfma_gemm512<<<dim3(4, Mc / 128), 256, 0, stream>>>(P1b, W2b, Sb, 1);
    // P3 = S @ W3^T            [fp32 out, N=50 padded to 64]
    mfma_gemm_p3<<<Mc / 128, 256, 0, stream>>>(Sb, W3b, P3);

    normalize_lens_kernel<<<1, 64, 0, stream>>>(lens_raw, lens);
    pool_softmax_kernel<<<Mc / 256, 256, 0, stream>>>(P3, lens, out_attn, out_smooth);
    class_inputs_kernel<<<dim3(Bc, Hc / 256, 8), 256, 0, stream>>>(out_attn, vals, out_class);
}

// Round 4
// 545.104 us; speedup vs baseline: 2.6472x; 1.1920x over previous
//
#include <hip/hip_runtime.h>
#include <cstdint>

// Problem constants
#define Bc 32
#define Lc 2048
#define Hc 512
#define Cc 50
#define Mc (Bc*Lc)   // 65536 rows

typedef short s8v   __attribute__((ext_vector_type(8)));   // 8 bf16 (4 VGPRs)
typedef float f4v   __attribute__((ext_vector_type(4)));   // MFMA C/D

__device__ inline unsigned short f2bf(float f) {            // RNE fp32->bf16
    unsigned int u = __float_as_uint(f);
    u += 0x7fffu + ((u >> 16) & 1u);
    return (unsigned short)(u >> 16);
}
__device__ inline float bf2f(unsigned short h) {
    return __uint_as_float(((unsigned int)h) << 16);
}
__device__ inline void gl_lds16(const unsigned short* g, unsigned short* l) {
    __builtin_amdgcn_global_load_lds(
        (const __attribute__((address_space(1))) unsigned int*)g,
        (__attribute__((address_space(3))) unsigned int*)l, 16, 0, 0);
}

// ---------------------------------------------------------------------------
// fp32 -> bf16 bulk convert (keys). 8 elements/thread.
// ---------------------------------------------------------------------------
__global__ __launch_bounds__(256)
void f32_to_bf16_kernel(const float* __restrict__ in, unsigned short* __restrict__ out)
{
    size_t i = ((size_t)blockIdx.x * 256 + threadIdx.x) * 8;
    float4 a = *(const float4*)(in + i);
    float4 b = *(const float4*)(in + i + 4);
    s8v o;
    o[0]=f2bf(a.x); o[1]=f2bf(a.y); o[2]=f2bf(a.z); o[3]=f2bf(a.w);
    o[4]=f2bf(b.x); o[5]=f2bf(b.y); o[6]=f2bf(b.z); o[7]=f2bf(b.w);
    *(s8v*)(out + i) = o;
}

// ---------------------------------------------------------------------------
// Convert W1, W2 -> bf16; W3 (50x512) -> bf16 padded to 64x512 (zero rows).
// ---------------------------------------------------------------------------
__global__ __launch_bounds__(256)
void convert_weights_kernel(const float* __restrict__ W1, const float* __restrict__ W2,
                            const float* __restrict__ W3,
                            unsigned short* __restrict__ W1b,
                            unsigned short* __restrict__ W2b,
                            unsigned short* __restrict__ W3b)
{
    int e = (blockIdx.x * 256 + threadIdx.x) * 8;
    if (e >= 524288) {                       // W3 padded region
        int off = e - 524288;
        int row = off >> 9;
        s8v o;
        #pragma unroll
        for (int j = 0; j < 8; ++j)
            o[j] = (row < Cc) ? (short)f2bf(W3[off + j]) : (short)0;
        *(s8v*)(W3b + off) = o;
        return;
    }
    const float* src = (e < 262144) ? W1 : W2;
    unsigned short* dst = (e < 262144) ? W1b : W2b;
    int off = (e < 262144) ? e : e - 262144;
    float4 a = *(const float4*)(src + off);
    float4 b = *(const float4*)(src + off + 4);
    s8v o;
    o[0]=f2bf(a.x); o[1]=f2bf(a.y); o[2]=f2bf(a.z); o[3]=f2bf(a.w);
    o[4]=f2bf(b.x); o[5]=f2bf(b.y); o[6]=f2bf(b.z); o[7]=f2bf(b.w);
    *(s8v*)(dst + off) = o;
}

// ---------------------------------------------------------------------------
// V (fp32, [b][l][h]) -> Vt (bf16, [b][h][l]).  64x64 LDS tile transpose.
// Load: lanes cover 64 B contiguous per row quad (full-line coalesced).
// LDS pitch 65 breaks pow-2 banking; read phase is 2-way aliased (free).
// Store: one wave-instr = 64 consecutive l's of one h row = 128 B coalesced.
// ---------------------------------------------------------------------------
__global__ __launch_bounds__(256)
void transpose_v_kernel(const float* __restrict__ V, unsigned short* __restrict__ Vt)
{
    __shared__ float tile[64 * 65];
    const int l0 = blockIdx.x * 64;
    const int h0 = blockIdx.y * 64;
    const int b  = blockIdx.z;
    const int tid = threadIdx.x;
    const int li = tid >> 2;          // 0..63
    const int hq = (tid & 3) * 4;     // 0,4,8,12

    const float* src = V + ((size_t)(b * Lc + l0 + li)) * Hc + h0 + hq;
    #pragma unroll
    for (int j = 0; j < 4; ++j) {
        float4 v = *(const float4*)(src + 16 * j);
        float* d = &tile[li * 65 + hq + 16 * j];
        d[0] = v.x; d[1] = v.y; d[2] = v.z; d[3] = v.w;
    }
    __syncthreads();

    const int lane = tid & 63;
    const int w    = tid >> 6;
    #pragma unroll
    for (int i = 0; i < 16; ++i) {
        int hr = i * 4 + w;           // h row within tile
        unsigned short* dst = Vt + ((size_t)(b * Hc + h0 + hr)) * Lc + l0 + lane;
        *dst = f2bf(tile[lane * 65 + hr]);
    }
}

// ---------------------------------------------------------------------------
// MFMA GEMM: Out = f(A @ W^T), 128x128 tile, BK=32, m97 structure (unchanged).
// mode 0: Out = bf16(tanh(acc)); mode 1: Out = bf16(A[m,j] + tanh(acc))
// ---------------------------------------------------------------------------
__global__ __launch_bounds__(256)
void mfma_gemm512(const unsigned short* __restrict__ Ab,
                  const unsigned short* __restrict__ Wb,
                  unsigned short* __restrict__ Ob, int mode)
{
    __shared__ alignas(16) unsigned short As[128 * 32];
    __shared__ alignas(16) unsigned short Bs[128 * 32];
    const int tid = threadIdx.x;
    const int w = tid >> 6, l = tid & 63;
    const int j0 = blockIdx.x * 128;
    const int i0 = blockIdx.y * 128;

    const int sr  = w * 16 + (l >> 2);
    const int kg8 = (l & 3) * 8;
    const unsigned short* Ag0 = Ab + (size_t)(i0 + sr) * 512 + kg8;
    const unsigned short* Ag1 = Ag0 + (size_t)64 * 512;
    const unsigned short* Bg0 = Wb + (size_t)(j0 + sr) * 512 + kg8;
    const unsigned short* Bg1 = Bg0 + (size_t)64 * 512;
    unsigned short* Al0 = As + w * 512;
    unsigned short* Al1 = As + 2048 + w * 512;
    unsigned short* Bl0 = Bs + w * 512;
    unsigned short* Bl1 = Bs + 2048 + w * 512;

    const int wm = (w & 1) * 64, wn = (w >> 1) * 64;
    const int fr = l & 15;
    const int fq = (l >> 4) * 8;

    f4v acc[4][4];
    #pragma unroll
    for (int r = 0; r < 4; ++r)
        #pragma unroll
        for (int c = 0; c < 4; ++c) acc[r][c] = (f4v){0.f, 0.f, 0.f, 0.f};

    for (int k0 = 0; k0 < 512; k0 += 32) {
        gl_lds16(Ag0 + k0, Al0);
        gl_lds16(Ag1 + k0, Al1);
        gl_lds16(Bg0 + k0, Bl0);
        gl_lds16(Bg1 + k0, Bl1);
        __syncthreads();
        s8v af[4], bf[4];
        #pragma unroll
        for (int r = 0; r < 4; ++r)
            af[r] = *(const s8v*)&As[(wm + r * 16 + fr) * 32 + fq];
        #pragma unroll
        for (int c = 0; c < 4; ++c)
            bf[c] = *(const s8v*)&Bs[(wn + c * 16 + fr) * 32 + fq];
        #pragma unroll
        for (int r = 0; r < 4; ++r)
            #pragma unroll
            for (int c = 0; c < 4; ++c)
                acc[r][c] = __builtin_amdgcn_mfma_f32_16x16x32_bf16(
                    af[r], bf[c], acc[r][c], 0, 0, 0);
        __syncthreads();
    }

    #pragma unroll
    for (int r = 0; r < 4; ++r)
        #pragma unroll
        for (int v = 0; v < 4; ++v) {
            const int row = i0 + wm + r * 16 + (l >> 4) * 4 + v;
            #pragma unroll
            for (int c = 0; c < 4; ++c) {
                const int col = j0 + wn + c * 16 + fr;
                float x = tanhf(acc[r][c][v]);
                if (mode) x += bf2f(Ab[(size_t)row * 512 + col]);
                Ob[(size_t)row * 512 + col] = f2bf(x);
            }
        }
}

// ---------------------------------------------------------------------------
// MFMA GEMM3: P3 = S @ W3^T (N=50 padded 64), fp32 out. (unchanged)
// ---------------------------------------------------------------------------
__global__ __launch_bounds__(256)
void mfma_gemm_p3(const unsigned short* __restrict__ Sb,
                  const unsigned short* __restrict__ W3b,
                  float* __restrict__ P3)
{
    __shared__ alignas(16) unsigned short As[128 * 32];
    __shared__ alignas(16) unsigned short Bs[64 * 32];
    const int tid = threadIdx.x;
    const int w = tid >> 6, l = tid & 63;
    const int i0 = blockIdx.x * 128;

    const int sr  = w * 16 + (l >> 2);
    const int kg8 = (l & 3) * 8;
    const unsigned short* Ag0 = Sb + (size_t)(i0 + sr) * 512 + kg8;
    const unsigned short* Ag1 = Ag0 + (size_t)64 * 512;
    const unsigned short* Bg  = W3b + (size_t)sr * 512 + kg8;
    unsigned short* Al0 = As + w * 512;
    unsigned short* Al1 = As + 2048 + w * 512;
    unsigned short* Bl  = Bs + w * 512;

    const int wm = w * 32;
    const int fr = l & 15;
    const int fq = (l >> 4) * 8;

    f4v acc[2][4];
    #pragma unroll
    for (int r = 0; r < 2; ++r)
        #pragma unroll
        for (int c = 0; c < 4; ++c) acc[r][c] = (f4v){0.f, 0.f, 0.f, 0.f};

    for (int k0 = 0; k0 < 512; k0 += 32) {
        gl_lds16(Ag0 + k0, Al0);
        gl_lds16(Ag1 + k0, Al1);
        gl_lds16(Bg + k0, Bl);
        __syncthreads();
        s8v af[2], bf[4];
        #pragma unroll
        for (int r = 0; r < 2; ++r)
            af[r] = *(const s8v*)&As[(wm + r * 16 + fr) * 32 + fq];
        #pragma unroll
        for (int c = 0; c < 4; ++c)
            bf[c] = *(const s8v*)&Bs[(c * 16 + fr) * 32 + fq];
        #pragma unroll
        for (int r = 0; r < 2; ++r)
            #pragma unroll
            for (int c = 0; c < 4; ++c)
                acc[r][c] = __builtin_amdgcn_mfma_f32_16x16x32_bf16(
                    af[r], bf[c], acc[r][c], 0, 0, 0);
        __syncthreads();
    }

    #pragma unroll
    for (int r = 0; r < 2; ++r)
        #pragma unroll
        for (int v = 0; v < 4; ++v) {
            const int row = i0 + wm + r * 16 + (l >> 4) * 4 + v;
            #pragma unroll
            for (int c = 0; c < 4; ++c) {
                const int col = c * 16 + fr;
                if (col < Cc) P3[(size_t)row * Cc + col] = acc[r][c][v];
            }
        }
}

// ---------------------------------------------------------------------------
// sent_lens dtype hedge (int64 vs int32 auto-detect).
// ---------------------------------------------------------------------------
__global__ __launch_bounds__(64)
void normalize_lens_kernel(const int* __restrict__ raw, int* __restrict__ lens)
{
    __shared__ int is64;
    if (threadIdx.x == 0) {
        int orv = 0;
        for (int i = 1; i < 32; i += 2) orv |= raw[i];
        is64 = (orv == 0) ? 1 : 0;
    }
    __syncthreads();
    int b = threadIdx.x;
    if (b < Bc) lens[b] = is64 ? raw[2*b] : raw[b];
}

// ---------------------------------------------------------------------------
// kq-fill + avgpool3(count_include_pad=False) + softmax + mask.
// NEW: also writes attnT (bf16, [b][c][l], c padded to 64 rows; rows 50..63
// left unwritten -> only affect discarded MFMA D rows). Lanes = consecutive
// l -> each c store is a coalesced 128 B wave-instr.
// ---------------------------------------------------------------------------
__global__ __launch_bounds__(256)
void pool_softmax_kernel(const float* __restrict__ P3, const int* __restrict__ lens,
                         float* __restrict__ out_attn, float* __restrict__ out_smooth,
                         unsigned short* __restrict__ attnT)
{
    const int idx = blockIdx.x * 256 + threadIdx.x;   // b*L + l
    const int b = idx >> 11;
    const int l = idx & (Lc - 1);
    const int len = lens[b];
    const float* base = P3 + (size_t)b * Lc * Cc;

    const int  r0 = min(l, len - 1);
    const bool hm = (l > 0);
    const bool hp = (l < Lc - 1);
    const int  rm = hm ? min(l - 1, len - 1) : 0;
    const int  rp = hp ? min(l + 1, len - 1) : 0;
    const float cnt = 1.f + (hm ? 1.f : 0.f) + (hp ? 1.f : 0.f);

    float sm[Cc];
    float mx = -1e30f;
    #pragma unroll
    for (int c = 0; c < Cc; ++c) {
        float s = base[(size_t)r0 * Cc + c];
        if (hm) s += base[(size_t)rm * Cc + c];
        if (hp) s += base[(size_t)rp * Cc + c];
        s = s / cnt;
        sm[c] = s;
        mx = fmaxf(mx, s);
    }
    float* srow = out_smooth + (size_t)idx * Cc;
    #pragma unroll
    for (int c = 0; c < Cc; ++c) srow[c] = sm[c];

    float sum = 0.f;
    #pragma unroll
    for (int c = 0; c < Cc; ++c) {
        float e = __expf(sm[c] - mx);
        sm[c] = e;
        sum += e;
    }
    const float inv = 1.f / sum;
    const bool valid = (l < len);
    float* arow = out_attn + (size_t)idx * Cc;
    unsigned short* trow = attnT + (size_t)b * 64 * Lc + l;
    #pragma unroll
    for (int c = 0; c < Cc; ++c) {
        float a = valid ? sm[c] * inv : 0.f;
        arow[c] = a;
        trow[(size_t)c * Lc] = f2bf(a);
    }
}

// ---------------------------------------------------------------------------
// class_inputs[b,c,h] = sum_l attn[b,l,c] * V[b,l,h]  -- v4: MFMA.
// Per batch: D(64x512) = attnT(64x2048) @ Vt(512x2048)^T, both bf16 [row][k].
// Tile M=64, N=128, K-split 4 (K-chunk 512, BK=32). 256 thr = 4 waves, wave w
// handles n-quarter w*32 (4x2 mfma tiles, 32 acc VGPRs). gl_lds16 staging.
// fp32 atomicAdd epilogue into pre-zeroed out_class (rows c>=50 discarded).
// ---------------------------------------------------------------------------
__global__ __launch_bounds__(256)
void class_mfma_kernel(const unsigned short* __restrict__ attnT,
                       const unsigned short* __restrict__ Vt,
                       float* __restrict__ out_class)
{
    __shared__ alignas(16) unsigned short As[64 * 32];    // 4 KB
    __shared__ alignas(16) unsigned short Bs[128 * 32];   // 8 KB
    const int tid = threadIdx.x;
    const int w = tid >> 6, l = tid & 63;
    const int n0 = blockIdx.x * 128;
    const int b  = blockIdx.y;
    const int kb = blockIdx.z * 512;

    const int sr  = w * 16 + (l >> 2);   // 0..63
    const int kg8 = (l & 3) * 8;
    const unsigned short* Ag  = attnT + ((size_t)b * 64 + sr) * Lc + kg8;
    const unsigned short* Bg0 = Vt + ((size_t)(b * Hc + n0 + sr)) * Lc + kg8;
    const unsigned short* Bg1 = Bg0 + (size_t)64 * Lc;
    unsigned short* Al  = As + w * 512;
    unsigned short* Bl0 = Bs + w * 512;
    unsigned short* Bl1 = Bs + 2048 + w * 512;

    const int fr = l & 15;
    const int fq = (l >> 4) * 8;

    f4v acc[4][2];
    #pragma unroll
    for (int r = 0; r < 4; ++r)
        #pragma unroll
        for (int c = 0; c < 2; ++c) acc[r][c] = (f4v){0.f, 0.f, 0.f, 0.f};

    for (int k0 = kb; k0 < kb + 512; k0 += 32) {
        gl_lds16(Ag + k0, Al);
        gl_lds16(Bg0 + k0, Bl0);
        gl_lds16(Bg1 + k0, Bl1);
        __syncthreads();
        s8v af[4], bf[2];
        #pragma unroll
        for (int r = 0; r < 4; ++r)
            af[r] = *(const s8v*)&As[(r * 16 + fr) * 32 + fq];
        #pragma unroll
        for (int c = 0; c < 2; ++c)
            bf[c] = *(const s8v*)&Bs[(w * 32 + c * 16 + fr) * 32 + fq];
        #pragma unroll
        for (int r = 0; r < 4; ++r)
            #pragma unroll
            for (int c = 0; c < 2; ++c)
                acc[r][c] = __builtin_amdgcn_mfma_f32_16x16x32_bf16(
                    af[r], bf[c], acc[r][c], 0, 0, 0);
        __syncthreads();
    }

    #pragma unroll
    for (int r = 0; r < 4; ++r)
        #pragma unroll
        for (int v = 0; v < 4; ++v) {
            const int m = r * 16 + (l >> 4) * 4 + v;   // class index
            if (m < Cc) {
                #pragma unroll
                for (int c = 0; c < 2; ++c) {
                    const int h = n0 + w * 32 + c * 16 + fr;
                    atomicAdd(out_class + ((size_t)b * Cc + m) * Hc + h,
                              acc[r][c][v]);
                }
            }
        }
}

// ---------------------------------------------------------------------------
// Workspace layout (~202 MiB, overlays exploit stream ordering):
//   off 0      : Akv bf16 (64 MiB)      -> later P3 fp32 (12.5 MiB)
//   off 64 MiB : P1b bf16 (64 MiB)      -> later Vt bf16 (64 MiB)
//   off 128 MiB: Sb  bf16 (64 MiB)
//   off 192 MiB: W1b, W2b (0.5 MiB each), W3b (64 KiB)
//   off 194 MiB: attnT bf16 32x64x2048 (8 MiB)
//   off 202 MiB: lens (128 B)
// ---------------------------------------------------------------------------
extern "C" void kernel_launch(void* const* d_in, const int* in_sizes, int n_in,
                              void* d_out, int out_size, void* d_ws, size_t ws_size,
                              hipStream_t stream)
{
    const float* keys     = (const float*)d_in[0];
    const float* vals     = (const float*)d_in[1];
    const int*   lens_raw = (const int*)d_in[2];
    const float* W1       = (const float*)d_in[3];
    const float* W2       = (const float*)d_in[4];
    const float* W3       = (const float*)d_in[5];

    char* ws = (char*)d_ws;
    const size_t MB = 1024 * 1024;
    unsigned short* Akv  = (unsigned short*)ws;
    float*          P3   = (float*)ws;                       // over Akv (dead)
    unsigned short* P1b  = (unsigned short*)(ws + 64 * MB);
    unsigned short* Vt   = (unsigned short*)(ws + 64 * MB);  // over P1b (dead)
    unsigned short* Sb   = (unsigned short*)(ws + 128 * MB);
    unsigned short* W1b  = (unsigned short*)(ws + 192 * MB);
    unsigned short* W2b  = W1b + Hc * Hc;
    unsigned short* W3b  = W2b + Hc * Hc;
    unsigned short* attnT= (unsigned short*)(ws + 194 * MB);
    int*            lens = (int*)(ws + 202 * MB);

    float* out_attn   = (float*)d_out;
    float* out_class  = out_attn + (size_t)Bc * Lc * Cc;
    float* out_smooth = out_class + (size_t)Bc * Cc * Hc;

    hipMemsetAsync(out_class, 0, (size_t)Bc * Cc * Hc * sizeof(float), stream);

    f32_to_bf16_kernel<<<(Mc * Hc / 8) / 256, 256, 0, stream>>>(keys, Akv);
    convert_weights_kernel<<<272, 256, 0, stream>>>(W1, W2, W3, W1b, W2b, W3b);
    normalize_lens_kernel<<<1, 64, 0, stream>>>(lens_raw, lens);

    // P1 = tanh(keys @ W1^T)   [bf16 out]
    mfma_gemm512<<<dim3(4, Mc / 128), 256, 0, stream>>>(Akv, W1b, P1b, 0);
    // S = P1 + tanh(P1 @ W2^T) [bf16 out]
    mfma_gemm512<<<dim3(4, Mc / 128), 256, 0, stream>>>(P1b, W2b, Sb, 1);
    // Vt = transpose(bf16(vals))  (P1b dead now; Vt overlays it)
    transpose_v_kernel<<<dim3(Lc / 64, Hc / 64, Bc), 256, 0, stream>>>(vals, Vt);
    // P3 = S @ W3^T            [fp32 out, overlays dead Akv]
    mfma_gemm_p3<<<Mc / 128, 256, 0, stream>>>(Sb, W3b, P3);
    // pool + softmax + mask; also emits attnT bf16
    pool_softmax_kernel<<<Mc / 256, 256, 0, stream>>>(P3, lens, out_attn, out_smooth, attnT);
    // class_inputs = attnT @ Vt^T per batch (MFMA, K-split 4, atomic reduce)
    class_mfma_kernel<<<dim3(4, Bc, 4), 256, 0, stream>>>(attnT, Vt, out_class);
}

// Round 5
// 524.127 us; speedup vs baseline: 2.7532x; 1.0400x over previous
//
#include <hip/hip_runtime.h>
#include <cstdint>

// Problem constants
#define Bc 32
#define Lc 2048
#define Hc 512
#define Cc 50
#define PCc 52        // P3 row stride (52 floats = 208 B, 16B-aligned)
#define Mc (Bc*Lc)    // 65536 rows

typedef short s8v   __attribute__((ext_vector_type(8)));   // 8 bf16 (4 VGPRs)
typedef float f4v   __attribute__((ext_vector_type(4)));   // MFMA C/D

__device__ inline unsigned short f2bf(float f) {            // RNE fp32->bf16
    unsigned int u = __float_as_uint(f);
    u += 0x7fffu + ((u >> 16) & 1u);
    return (unsigned short)(u >> 16);
}
__device__ inline float bf2f(unsigned short h) {
    return __uint_as_float(((unsigned int)h) << 16);
}
// tanh(x) = 1 - 2/(e^{2x}+1): ~5 VALU ops (mul, v_exp, add, rcp, fma).
// Saturates exactly (+inf -> 1, 0 -> -1); abs err ~1e-5 << bf16 rounding.
__device__ inline float fast_tanh(float x) {
    float e = __expf(2.0f * x);
    return 1.0f - 2.0f / (e + 1.0f);
}
__device__ inline void gl_lds16(const unsigned short* g, unsigned short* l) {
    __builtin_amdgcn_global_load_lds(
        (const __attribute__((address_space(1))) unsigned int*)g,
        (__attribute__((address_space(3))) unsigned int*)l, 16, 0, 0);
}

// ---------------------------------------------------------------------------
// fp32 -> bf16 bulk convert (keys). 8 elements/thread.
// ---------------------------------------------------------------------------
__global__ __launch_bounds__(256)
void f32_to_bf16_kernel(const float* __restrict__ in, unsigned short* __restrict__ out)
{
    size_t i = ((size_t)blockIdx.x * 256 + threadIdx.x) * 8;
    float4 a = *(const float4*)(in + i);
    float4 b = *(const float4*)(in + i + 4);
    s8v o;
    o[0]=f2bf(a.x); o[1]=f2bf(a.y); o[2]=f2bf(a.z); o[3]=f2bf(a.w);
    o[4]=f2bf(b.x); o[5]=f2bf(b.y); o[6]=f2bf(b.z); o[7]=f2bf(b.w);
    *(s8v*)(out + i) = o;
}

// ---------------------------------------------------------------------------
// Convert W1, W2 -> bf16; W3 (50x512) -> bf16 padded to 64x512 (zero rows).
// ---------------------------------------------------------------------------
__global__ __launch_bounds__(256)
void convert_weights_kernel(const float* __restrict__ W1, const float* __restrict__ W2,
                            const float* __restrict__ W3,
                            unsigned short* __restrict__ W1b,
                            unsigned short* __restrict__ W2b,
                            unsigned short* __restrict__ W3b)
{
    int e = (blockIdx.x * 256 + threadIdx.x) * 8;
    if (e >= 524288) {                       // W3 padded region
        int off = e - 524288;
        int row = off >> 9;
        s8v o;
        #pragma unroll
        for (int j = 0; j < 8; ++j)
            o[j] = (row < Cc) ? (short)f2bf(W3[off + j]) : (short)0;
        *(s8v*)(W3b + off) = o;
        return;
    }
    const float* src = (e < 262144) ? W1 : W2;
    unsigned short* dst = (e < 262144) ? W1b : W2b;
    int off = (e < 262144) ? e : e - 262144;
    float4 a = *(const float4*)(src + off);
    float4 b = *(const float4*)(src + off + 4);
    s8v o;
    o[0]=f2bf(a.x); o[1]=f2bf(a.y); o[2]=f2bf(a.z); o[3]=f2bf(a.w);
    o[4]=f2bf(b.x); o[5]=f2bf(b.y); o[6]=f2bf(b.z); o[7]=f2bf(b.w);
    *(s8v*)(dst + off) = o;
}

// ---------------------------------------------------------------------------
// V (fp32, [b][l][h]) -> Vt (bf16, [b][h][l]).  64x64 LDS tile transpose.
// ---------------------------------------------------------------------------
__global__ __launch_bounds__(256)
void transpose_v_kernel(const float* __restrict__ V, unsigned short* __restrict__ Vt)
{
    __shared__ float tile[64 * 65];
    const int l0 = blockIdx.x * 64;
    const int h0 = blockIdx.y * 64;
    const int b  = blockIdx.z;
    const int tid = threadIdx.x;
    const int li = tid >> 2;          // 0..63
    const int hq = (tid & 3) * 4;     // 0,4,8,12

    const float* src = V + ((size_t)(b * Lc + l0 + li)) * Hc + h0 + hq;
    #pragma unroll
    for (int j = 0; j < 4; ++j) {
        float4 v = *(const float4*)(src + 16 * j);
        float* d = &tile[li * 65 + hq + 16 * j];
        d[0] = v.x; d[1] = v.y; d[2] = v.z; d[3] = v.w;
    }
    __syncthreads();

    const int lane = tid & 63;
    const int w    = tid >> 6;
    #pragma unroll
    for (int i = 0; i < 16; ++i) {
        int hr = i * 4 + w;           // h row within tile
        unsigned short* dst = Vt + ((size_t)(b * Hc + h0 + hr)) * Lc + l0 + lane;
        *dst = f2bf(tile[lane * 65 + hr]);
    }
}

// ---------------------------------------------------------------------------
// MFMA GEMM: Out = f(A @ W^T), 128x128 tile, BK=32, m97 structure.
// mode 0: Out = bf16(fast_tanh(acc)); mode 1: Out = bf16(A[m,j]+fast_tanh(acc))
// ---------------------------------------------------------------------------
__global__ __launch_bounds__(256)
void mfma_gemm512(const unsigned short* __restrict__ Ab,
                  const unsigned short* __restrict__ Wb,
                  unsigned short* __restrict__ Ob, int mode)
{
    __shared__ alignas(16) unsigned short As[128 * 32];
    __shared__ alignas(16) unsigned short Bs[128 * 32];
    const int tid = threadIdx.x;
    const int w = tid >> 6, l = tid & 63;
    const int j0 = blockIdx.x * 128;
    const int i0 = blockIdx.y * 128;

    const int sr  = w * 16 + (l >> 2);
    const int kg8 = (l & 3) * 8;
    const unsigned short* Ag0 = Ab + (size_t)(i0 + sr) * 512 + kg8;
    const unsigned short* Ag1 = Ag0 + (size_t)64 * 512;
    const unsigned short* Bg0 = Wb + (size_t)(j0 + sr) * 512 + kg8;
    const unsigned short* Bg1 = Bg0 + (size_t)64 * 512;
    unsigned short* Al0 = As + w * 512;
    unsigned short* Al1 = As + 2048 + w * 512;
    unsigned short* Bl0 = Bs + w * 512;
    unsigned short* Bl1 = Bs + 2048 + w * 512;

    const int wm = (w & 1) * 64, wn = (w >> 1) * 64;
    const int fr = l & 15;
    const int fq = (l >> 4) * 8;

    f4v acc[4][4];
    #pragma unroll
    for (int r = 0; r < 4; ++r)
        #pragma unroll
        for (int c = 0; c < 4; ++c) acc[r][c] = (f4v){0.f, 0.f, 0.f, 0.f};

    for (int k0 = 0; k0 < 512; k0 += 32) {
        gl_lds16(Ag0 + k0, Al0);
        gl_lds16(Ag1 + k0, Al1);
        gl_lds16(Bg0 + k0, Bl0);
        gl_lds16(Bg1 + k0, Bl1);
        __syncthreads();
        s8v af[4], bf[4];
        #pragma unroll
        for (int r = 0; r < 4; ++r)
            af[r] = *(const s8v*)&As[(wm + r * 16 + fr) * 32 + fq];
        #pragma unroll
        for (int c = 0; c < 4; ++c)
            bf[c] = *(const s8v*)&Bs[(wn + c * 16 + fr) * 32 + fq];
        #pragma unroll
        for (int r = 0; r < 4; ++r)
            #pragma unroll
            for (int c = 0; c < 4; ++c)
                acc[r][c] = __builtin_amdgcn_mfma_f32_16x16x32_bf16(
                    af[r], bf[c], acc[r][c], 0, 0, 0);
        __syncthreads();
    }

    #pragma unroll
    for (int r = 0; r < 4; ++r)
        #pragma unroll
        for (int v = 0; v < 4; ++v) {
            const int row = i0 + wm + r * 16 + (l >> 4) * 4 + v;
            #pragma unroll
            for (int c = 0; c < 4; ++c) {
                const int col = j0 + wn + c * 16 + fr;
                float x = fast_tanh(acc[r][c][v]);
                if (mode) x += bf2f(Ab[(size_t)row * 512 + col]);
                Ob[(size_t)row * 512 + col] = f2bf(x);
            }
        }
}

// ---------------------------------------------------------------------------
// MFMA GEMM3: P3 = S @ W3^T (N=50 padded 64), fp32 out, row stride PCc=52.
// ---------------------------------------------------------------------------
__global__ __launch_bounds__(256)
void mfma_gemm_p3(const unsigned short* __restrict__ Sb,
                  const unsigned short* __restrict__ W3b,
                  float* __restrict__ P3)
{
    __shared__ alignas(16) unsigned short As[128 * 32];
    __shared__ alignas(16) unsigned short Bs[64 * 32];
    const int tid = threadIdx.x;
    const int w = tid >> 6, l = tid & 63;
    const int i0 = blockIdx.x * 128;

    const int sr  = w * 16 + (l >> 2);
    const int kg8 = (l & 3) * 8;
    const unsigned short* Ag0 = Sb + (size_t)(i0 + sr) * 512 + kg8;
    const unsigned short* Ag1 = Ag0 + (size_t)64 * 512;
    const unsigned short* Bg  = W3b + (size_t)sr * 512 + kg8;
    unsigned short* Al0 = As + w * 512;
    unsigned short* Al1 = As + 2048 + w * 512;
    unsigned short* Bl  = Bs + w * 512;

    const int wm = w * 32;
    const int fr = l & 15;
    const int fq = (l >> 4) * 8;

    f4v acc[2][4];
    #pragma unroll
    for (int r = 0; r < 2; ++r)
        #pragma unroll
        for (int c = 0; c < 4; ++c) acc[r][c] = (f4v){0.f, 0.f, 0.f, 0.f};

    for (int k0 = 0; k0 < 512; k0 += 32) {
        gl_lds16(Ag0 + k0, Al0);
        gl_lds16(Ag1 + k0, Al1);
        gl_lds16(Bg + k0, Bl);
        __syncthreads();
        s8v af[2], bf[4];
        #pragma unroll
        for (int r = 0; r < 2; ++r)
            af[r] = *(const s8v*)&As[(wm + r * 16 + fr) * 32 + fq];
        #pragma unroll
        for (int c = 0; c < 4; ++c)
            bf[c] = *(const s8v*)&Bs[(c * 16 + fr) * 32 + fq];
        #pragma unroll
        for (int r = 0; r < 2; ++r)
            #pragma unroll
            for (int c = 0; c < 4; ++c)
                acc[r][c] = __builtin_amdgcn_mfma_f32_16x16x32_bf16(
                    af[r], bf[c], acc[r][c], 0, 0, 0);
        __syncthreads();
    }

    #pragma unroll
    for (int r = 0; r < 2; ++r)
        #pragma unroll
        for (int v = 0; v < 4; ++v) {
            const int row = i0 + wm + r * 16 + (l >> 4) * 4 + v;
            #pragma unroll
            for (int c = 0; c < 4; ++c) {
                const int col = c * 16 + fr;
                if (col < Cc) P3[(size_t)row * PCc + col] = acc[r][c][v];
            }
        }
}

// ---------------------------------------------------------------------------
// sent_lens dtype hedge (int64 vs int32 auto-detect).
// ---------------------------------------------------------------------------
__global__ __launch_bounds__(64)
void normalize_lens_kernel(const int* __restrict__ raw, int* __restrict__ lens)
{
    __shared__ int is64;
    if (threadIdx.x == 0) {
        int orv = 0;
        for (int i = 1; i < 32; i += 2) orv |= raw[i];
        is64 = (orv == 0) ? 1 : 0;
    }
    __syncthreads();
    int b = threadIdx.x;
    if (b < Bc) lens[b] = is64 ? raw[2*b] : raw[b];
}

// ---------------------------------------------------------------------------
// kq-fill + avgpool3(count_include_pad=False) + softmax + mask.
// P3 rows padded to 52 floats -> 13 dwordx4 loads per row (vs 50 scalar).
// attn/smooth rows stored as 25 float2 each. attnT stores stay scalar
// (coalesced across lanes: consecutive l -> 128 B per wave-instr).
// Pad cols 50/51 are garbage but never used in pool/softmax math.
// ---------------------------------------------------------------------------
__global__ __launch_bounds__(256)
void pool_softmax_kernel(const float* __restrict__ P3, const int* __restrict__ lens,
                         float* __restrict__ out_attn, float* __restrict__ out_smooth,
                         unsigned short* __restrict__ attnT)
{
    const int idx = blockIdx.x * 256 + threadIdx.x;   // b*L + l
    const int b = idx >> 11;
    const int l = idx & (Lc - 1);
    const int len = lens[b];
    const float* base = P3 + (size_t)b * Lc * PCc;

    const int  r0 = min(l, len - 1);
    const bool hm = (l > 0);
    const bool hp = (l < Lc - 1);
    const int  rm = hm ? min(l - 1, len - 1) : 0;
    const int  rp = hp ? min(l + 1, len - 1) : 0;
    const float rcnt = 1.f / (1.f + (hm ? 1.f : 0.f) + (hp ? 1.f : 0.f));

    float sm[PCc];
    const float* p0 = base + (size_t)r0 * PCc;
    #pragma unroll
    for (int q = 0; q < 13; ++q) {
        f4v v = *(const f4v*)(p0 + q * 4);
        sm[q*4+0] = v[0]; sm[q*4+1] = v[1]; sm[q*4+2] = v[2]; sm[q*4+3] = v[3];
    }
    if (hm) {
        const float* p = base + (size_t)rm * PCc;
        #pragma unroll
        for (int q = 0; q < 13; ++q) {
            f4v v = *(const f4v*)(p + q * 4);
            sm[q*4+0] += v[0]; sm[q*4+1] += v[1]; sm[q*4+2] += v[2]; sm[q*4+3] += v[3];
        }
    }
    if (hp) {
        const float* p = base + (size_t)rp * PCc;
        #pragma unroll
        for (int q = 0; q < 13; ++q) {
            f4v v = *(const f4v*)(p + q * 4);
            sm[q*4+0] += v[0]; sm[q*4+1] += v[1]; sm[q*4+2] += v[2]; sm[q*4+3] += v[3];
        }
    }

    float mx = -1e30f;
    #pragma unroll
    for (int c = 0; c < Cc; ++c) {
        sm[c] *= rcnt;
        mx = fmaxf(mx, sm[c]);
    }
    float* srow = out_smooth + (size_t)idx * Cc;
    #pragma unroll
    for (int q = 0; q < 25; ++q) {
        float2 v = make_float2(sm[q*2], sm[q*2+1]);
        *(float2*)(srow + q * 2) = v;
    }

    float sum = 0.f;
    #pragma unroll
    for (int c = 0; c < Cc; ++c) {
        float e = __expf(sm[c] - mx);
        sm[c] = e;
        sum += e;
    }
    const float inv = 1.f / sum;
    const bool valid = (l < len);
    const float scale = valid ? inv : 0.f;
    float* arow = out_attn + (size_t)idx * Cc;
    unsigned short* trow = attnT + (size_t)b * 64 * Lc + l;
    #pragma unroll
    for (int c = 0; c < Cc; ++c) sm[c] *= scale;
    #pragma unroll
    for (int q = 0; q < 25; ++q)
        *(float2*)(arow + q * 2) = make_float2(sm[q*2], sm[q*2+1]);
    #pragma unroll
    for (int c = 0; c < Cc; ++c)
        trow[(size_t)c * Lc] = f2bf(sm[c]);
}

// ---------------------------------------------------------------------------
// class_inputs[b,c,h] = sum_l attn[b,l,c] * V[b,l,h]  -- MFMA (unchanged).
// ---------------------------------------------------------------------------
__global__ __launch_bounds__(256)
void class_mfma_kernel(const unsigned short* __restrict__ attnT,
                       const unsigned short* __restrict__ Vt,
                       float* __restrict__ out_class)
{
    __shared__ alignas(16) unsigned short As[64 * 32];    // 4 KB
    __shared__ alignas(16) unsigned short Bs[128 * 32];   // 8 KB
    const int tid = threadIdx.x;
    const int w = tid >> 6, l = tid & 63;
    const int n0 = blockIdx.x * 128;
    const int b  = blockIdx.y;
    const int kb = blockIdx.z * 512;

    const int sr  = w * 16 + (l >> 2);   // 0..63
    const int kg8 = (l & 3) * 8;
    const unsigned short* Ag  = attnT + ((size_t)b * 64 + sr) * Lc + kg8;
    const unsigned short* Bg0 = Vt + ((size_t)(b * Hc + n0 + sr)) * Lc + kg8;
    const unsigned short* Bg1 = Bg0 + (size_t)64 * Lc;
    unsigned short* Al  = As + w * 512;
    unsigned short* Bl0 = Bs + w * 512;
    unsigned short* Bl1 = Bs + 2048 + w * 512;

    const int fr = l & 15;
    const int fq = (l >> 4) * 8;

    f4v acc[4][2];
    #pragma unroll
    for (int r = 0; r < 4; ++r)
        #pragma unroll
        for (int c = 0; c < 2; ++c) acc[r][c] = (f4v){0.f, 0.f, 0.f, 0.f};

    for (int k0 = kb; k0 < kb + 512; k0 += 32) {
        gl_lds16(Ag + k0, Al);
        gl_lds16(Bg0 + k0, Bl0);
        gl_lds16(Bg1 + k0, Bl1);
        __syncthreads();
        s8v af[4], bf[2];
        #pragma unroll
        for (int r = 0; r < 4; ++r)
            af[r] = *(const s8v*)&As[(r * 16 + fr) * 32 + fq];
        #pragma unroll
        for (int c = 0; c < 2; ++c)
            bf[c] = *(const s8v*)&Bs[(w * 32 + c * 16 + fr) * 32 + fq];
        #pragma unroll
        for (int r = 0; r < 4; ++r)
            #pragma unroll
            for (int c = 0; c < 2; ++c)
                acc[r][c] = __builtin_amdgcn_mfma_f32_16x16x32_bf16(
                    af[r], bf[c], acc[r][c], 0, 0, 0);
        __syncthreads();
    }

    #pragma unroll
    for (int r = 0; r < 4; ++r)
        #pragma unroll
        for (int v = 0; v < 4; ++v) {
            const int m = r * 16 + (l >> 4) * 4 + v;   // class index
            if (m < Cc) {
                #pragma unroll
                for (int c = 0; c < 2; ++c) {
                    const int h = n0 + w * 32 + c * 16 + fr;
                    atomicAdd(out_class + ((size_t)b * Cc + m) * Hc + h,
                              acc[r][c][v]);
                }
            }
        }
}

// ---------------------------------------------------------------------------
// Workspace layout (~202 MiB, overlays exploit stream ordering):
//   off 0      : Akv bf16 (64 MiB)      -> later P3 fp32 stride-52 (13.6 MiB)
//   off 64 MiB : P1b bf16 (64 MiB)      -> later Vt bf16 (64 MiB)
//   off 128 MiB: Sb  bf16 (64 MiB)
//   off 192 MiB: W1b, W2b (0.5 MiB each), W3b (64 KiB)
//   off 194 MiB: attnT bf16 32x64x2048 (8 MiB)
//   off 202 MiB: lens (128 B)
// ---------------------------------------------------------------------------
extern "C" void kernel_launch(void* const* d_in, const int* in_sizes, int n_in,
                              void* d_out, int out_size, void* d_ws, size_t ws_size,
                              hipStream_t stream)
{
    const float* keys     = (const float*)d_in[0];
    const float* vals     = (const float*)d_in[1];
    const int*   lens_raw = (const int*)d_in[2];
    const float* W1       = (const float*)d_in[3];
    const float* W2       = (const float*)d_in[4];
    const float* W3       = (const float*)d_in[5];

    char* ws = (char*)d_ws;
    const size_t MB = 1024 * 1024;
    unsigned short* Akv  = (unsigned short*)ws;
    float*          P3   = (float*)ws;                       // over Akv (dead)
    unsigned short* P1b  = (unsigned short*)(ws + 64 * MB);
    unsigned short* Vt   = (unsigned short*)(ws + 64 * MB);  // over P1b (dead)
    unsigned short* Sb   = (unsigned short*)(ws + 128 * MB);
    unsigned short* W1b  = (unsigned short*)(ws + 192 * MB);
    unsigned short* W2b  = W1b + Hc * Hc;
    unsigned short* W3b  = W2b + Hc * Hc;
    unsigned short* attnT= (unsigned short*)(ws + 194 * MB);
    int*            lens = (int*)(ws + 202 * MB);

    float* out_attn   = (float*)d_out;
    float* out_class  = out_attn + (size_t)Bc * Lc * Cc;
    float* out_smooth = out_class + (size_t)Bc * Cc * Hc;

    hipMemsetAsync(out_class, 0, (size_t)Bc * Cc * Hc * sizeof(float), stream);

    f32_to_bf16_kernel<<<(Mc * Hc / 8) / 256, 256, 0, stream>>>(keys, Akv);
    convert_weights_kernel<<<272, 256, 0, stream>>>(W1, W2, W3, W1b, W2b, W3b);
    normalize_lens_kernel<<<1, 64, 0, stream>>>(lens_raw, lens);

    // P1 = tanh(keys @ W1^T)   [bf16 out]
    mfma_gemm512<<<dim3(4, Mc / 128), 256, 0, stream>>>(Akv, W1b, P1b, 0);
    // S = P1 + tanh(P1 @ W2^T) [bf16 out]
    mfma_gemm512<<<dim3(4, Mc / 128), 256, 0, stream>>>(P1b, W2b, Sb, 1);
    // Vt = transpose(bf16(vals))  (P1b dead now; Vt overlays it)
    transpose_v_kernel<<<dim3(Lc / 64, Hc / 64, Bc), 256, 0, stream>>>(vals, Vt);
    // P3 = S @ W3^T            [fp32 out, stride 52, overlays dead Akv]
    mfma_gemm_p3<<<Mc / 128, 256, 0, stream>>>(Sb, W3b, P3);
    // pool + softmax + mask; also emits attnT bf16
    pool_softmax_kernel<<<Mc / 256, 256, 0, stream>>>(P3, lens, out_attn, out_smooth, attnT);
    // class_inputs = attnT @ Vt^T per batch (MFMA, K-split 4, atomic reduce)
    class_mfma_kernel<<<dim3(4, Bc, 4), 256, 0, stream>>>(attnT, Vt, out_class);
}